// Round 7
// baseline (572.270 us; speedup 1.0000x reference)
//
#include <hip/hip_runtime.h>
#include <math.h>

// Problem constants (fixed by setup_inputs)
#define B_  32
#define N_  20000
#define C_  8
#define E_  512
#define H_  8
#define SCALE 0.125f   // 1/sqrt(64)

#define CHUNK 512
#define NCH   40       // ceil(20000/512)  (top-k chunking)
#define NC3   157      // ceil(20000/128)  (GEMM n-chunks, BN=128)
#define SSZ ((size_t)B_ * H_ * N_)   // per-class S floats (256*20000)

typedef __attribute__((ext_vector_type(8))) short bf8_t;   // 8 bf16 (4 VGPRs)
typedef __attribute__((ext_vector_type(4))) float f32x4;   // 16x16 MFMA acc

// async global->LDS, 16B per lane, wave-uniform LDS base + lane*16
#define GLOAD_LDS16(g, l)                                              \
    __builtin_amdgcn_global_load_lds(                                  \
        (const __attribute__((address_space(1))) unsigned int*)(g),    \
        (__attribute__((address_space(3))) unsigned int*)(l), 16, 0, 0)

#define WAITCNT_VM6 __builtin_amdgcn_s_waitcnt(0xF76)   // vmcnt(6), lgkm/exp no-wait
#define WAITCNT_VM0 __builtin_amdgcn_s_waitcnt(0xF70)   // vmcnt(0)

// RNE round-to-bf16 on bit patterns
__device__ inline unsigned short bf_round(float x, float& fv) {
    unsigned int u = __float_as_uint(x);
    unsigned int r = (u + 0x7fffu + ((u >> 16) & 1u)) & 0xffff0000u;
    fv = __uint_as_float(r);
    return (unsigned short)(r >> 16);
}

// ---------------------------------------------------------------------------
// K1a: q(c,b,f) = sum_e x(b,e) * Wq[c][f,e] + bq[c][f]
// Weight-stationary: block = (f-tile of 8, c); thread = (b, f_sub).
// ---------------------------------------------------------------------------
__global__ __launch_bounds__(256) void k_q2(
        const float* __restrict__ x, const float* __restrict__ Wq,
        const float* __restrict__ bq, float* __restrict__ q) {
    int ft = blockIdx.x, c = blockIdx.y;
    int f0 = ft * 8;
    __shared__ float wsm[8][66];
    __shared__ float xs[32][66];
    int tid = threadIdx.x;
    int b = tid & 31, fs = tid >> 5;
    float acc = 0.f;
    const float* W = Wq + (size_t)c * E_ * E_;
    for (int k0 = 0; k0 < E_; k0 += 64) {
        __syncthreads();
        for (int i = tid; i < 512; i += 256)
            wsm[i >> 6][i & 63] = W[(size_t)(f0 + (i >> 6)) * E_ + k0 + (i & 63)];
        for (int i = tid; i < 2048; i += 256)
            xs[i >> 6][i & 63] = x[(size_t)(i >> 6) * E_ + k0 + (i & 63)];
        __syncthreads();
        #pragma unroll
        for (int kk = 0; kk < 64; ++kk)
            acc += xs[b][kk] * wsm[fs][kk];
    }
    q[((size_t)c * B_ + b) * E_ + f0 + fs] = acc + bq[c * E_ + f0 + fs];
}

// ---------------------------------------------------------------------------
// K1b: u(c, m=(b*8+h), e) = sum_d q(c,b,h*64+d) * Wk[c][h*64+d, e]
// block = (e-tile of 64, h, c); thread = (b, e-group of 8). Wk read once.
// ---------------------------------------------------------------------------
__global__ __launch_bounds__(256) void k_u2(
        const float* __restrict__ q, const float* __restrict__ Wk,
        const float* __restrict__ bk, float* __restrict__ u,
        float* __restrict__ qb) {
    int et = blockIdx.x, h = blockIdx.y, c = blockIdx.z;
    int e0 = et * 64;
    __shared__ float qs[32][66];
    __shared__ float wk[64][66];
    int tid = threadIdx.x;
    int b = tid & 31, es = tid >> 5;
    for (int i = tid; i < 2048; i += 256)
        qs[i >> 6][i & 63] = q[((size_t)c * B_ + (i >> 6)) * E_ + h * 64 + (i & 63)];
    const float* W = Wk + (size_t)c * E_ * E_ + (size_t)(h * 64) * E_;
    for (int i = tid; i < 4096; i += 256)
        wk[i >> 6][i & 63] = W[(size_t)(i >> 6) * E_ + e0 + (i & 63)];
    __syncthreads();
    float acc[8] = {};
    for (int d = 0; d < 64; ++d) {
        float qv = qs[b][d];
        #pragma unroll
        for (int j = 0; j < 8; ++j)
            acc[j] += qv * wk[d][es * 8 + j];
    }
    float* urow = u + ((size_t)c * 256 + b * 8 + h) * E_ + e0 + es * 8;
    #pragma unroll
    for (int j = 0; j < 8; ++j) urow[j] = acc[j];
    if (et == 0 && es == 0) {
        float s = 0.f;
        const float* bkr = bk + c * E_ + h * 64;
        for (int d = 0; d < 64; ++d) s += qs[b][d] * bkr[d];
        qb[c * 256 + b * 8 + h] = s;
    }
}

// ---------------------------------------------------------------------------
// Split u into 3 bf16 planes in 16x16x32 A-fragment order:
//   u3[plane][c][mtile 16][kstep 16][lane 64][8]; lane*8+j holds
//   u[c][mtile*16 + (lane&15)][ks*32 + (lane>>4)*8 + j]
// ---------------------------------------------------------------------------
#define U3_PLANE ((size_t)C_ * 16 * 16 * 512)   // 1,048,576 shorts

__global__ void k_split_u3(const float* __restrict__ u, short* __restrict__ u3) {
    int bx = blockIdx.x;
    int ks = bx & 15, mt = (bx >> 4) & 15, c = bx >> 8;
    int lane = threadIdx.x;
    int m  = mt * 16 + (lane & 15);
    int k0 = ks * 32 + (lane >> 4) * 8;
    const float* up = u + ((size_t)c * 256 + m) * 512 + k0;
    size_t base = ((((size_t)c * 16 + mt) * 16 + ks) * 512) + (size_t)lane * 8;
    #pragma unroll
    for (int j = 0; j < 8; ++j) {
        float x = up[j], fh, fm, fl;
        unsigned short h = bf_round(x, fh);
        unsigned short mm = bf_round(x - fh, fm);
        unsigned short l = bf_round(x - fh - fm, fl);
        u3[base + j]                = (short)h;
        u3[U3_PLANE + base + j]     = (short)mm;
        u3[2 * U3_PLANE + base + j] = (short)l;
    }
}

// ---------------------------------------------------------------------------
// Split A into 3 bf16 planes, tiled per (nchunk of 128, kstep of 32):
//   [3][128 n][32 k] with within-row 16B-chunk swizzle: logical chunk q4 of
//   row n stored at chunk position (q4 + (n>>1))&3.  (R5 layout: measured
//   zero LDS bank conflicts for the 16x16 B-frag read pattern.)
// ---------------------------------------------------------------------------
__global__ void k_split_A3(const float* __restrict__ A, short* __restrict__ A3t) {
    int nc = blockIdx.x, ks = blockIdx.y;
    int tid = threadIdx.x;
    int n = tid >> 1, kg = (tid & 1) * 2;   // logical chunks kg, kg+1
    int gn = nc * 128 + n;
    const float* ap = A + (size_t)gn * 512 + ks * 32 + kg * 8;
    bf8_t vh[2], vm[2], vl[2];
    #pragma unroll
    for (int g = 0; g < 2; ++g)
        #pragma unroll
        for (int j = 0; j < 8; ++j) {
            float x = (gn < N_) ? ap[g * 8 + j] : 0.f;
            float fh, fm, fl;
            unsigned short h = bf_round(x, fh);
            unsigned short mm = bf_round(x - fh, fm);
            unsigned short l = bf_round(x - fh - fm, fl);
            vh[g][j] = (short)h; vm[g][j] = (short)mm; vl[g][j] = (short)l;
        }
    short* outp = A3t + ((size_t)nc * 16 + ks) * 12288 + n * 32;
    #pragma unroll
    for (int g = 0; g < 2; ++g) {
        int p = ((kg + g) + (n >> 1)) & 3;
        *(bf8_t*)(outp + p * 8)        = vh[g];
        *(bf8_t*)(outp + 4096 + p * 8) = vm[g];
        *(bf8_t*)(outp + 8192 + p * 8) = vl[g];
    }
}

// ---------------------------------------------------------------------------
// Main: S(m,n) = member ? exp(SCALE*(u·A + qb)) : 0, 6-product bf16x3 via
// 16x16x32 MFMA. Block: 256 thr (4 waves), tile M=256 x BN=128 per
// (class, nchunk). 2x2 wave blocking: wave w owns m-half (w>>1)*128 and
// n-half (w&1)*64 -> 12 B-frag LDS reads + 192 MFMA per wave per ks.
// Double-buffered LDS, async DMA staging, ONE barrier per ks-iter.
// ---------------------------------------------------------------------------
#define MFMA16(a, b, c) __builtin_amdgcn_mfma_f32_16x16x32_bf16(a, b, c, 0, 0, 0)

__global__ __launch_bounds__(256, 2) void k_scores_mfma(
        const short* __restrict__ u3, const short* __restrict__ A3t,
        const float* __restrict__ qb, const int* __restrict__ mask,
        float* __restrict__ S, float* __restrict__ Zpart, int c0, int CB) {
    __shared__ __align__(16) short As[2][12288];   // dbuf [3][128][32] swizzled
    __shared__ float sQb[256];
    __shared__ int   sMask[128];
    int bx = blockIdx.x;
    int z  = bx % CB;
    int c  = c0 + z;
    int nc = bx / CB;
    int tid = threadIdx.x;
    int lane = tid & 63, w = tid >> 6;
    int quad = lane >> 4, l15 = lane & 15;
    int mh = w >> 1, nh = w & 1;
    int n0 = nc * 128;

    sQb[tid] = qb[c * 256 + tid];
    if (tid < 128) {
        int n = n0 + tid;
        sMask[tid] = (n < N_) ? mask[(size_t)n * C_ + c] : 0;
    }

    f32x4 acc[8][4];   // [mt][nt]
    #pragma unroll
    for (int i = 0; i < 8; ++i)
        #pragma unroll
        for (int j = 0; j < 4; ++j)
            acc[i][j] = (f32x4){0.f, 0.f, 0.f, 0.f};

    const char* tileBase = (const char*)A3t + (size_t)nc * (16 * 24576);

    // prologue: DMA tile ks=0 -> As[0]
    #pragma unroll
    for (int t = 0; t < 6; ++t) {
        int seg = w * 6 + t;
        GLOAD_LDS16(tileBase + (size_t)seg * 1024 + lane * 16,
                    (char*)As[0] + seg * 1024);
    }

    for (int ks = 0; ks < 16; ++ks) {
        int cur = ks & 1;
        __syncthreads();   // waves done reading As[cur^1]; DMA(ks) drained
        if (ks < 15) {     // issue DMA for next tile into the other buffer
            const char* src = tileBase + (size_t)(ks + 1) * 24576;
            #pragma unroll
            for (int t = 0; t < 6; ++t) {
                int seg = w * 6 + t;
                GLOAD_LDS16(src + (size_t)seg * 1024 + lane * 16,
                            (char*)As[cur ^ 1] + seg * 1024);
            }
            WAITCNT_VM6;   // all but the 6 just-issued done => DMA(ks) landed
        } else {
            WAITCNT_VM0;
        }

        // B fragments for this wave's n-half (R5 zero-conflict pattern)
        bf8_t bf[4][3];
        #pragma unroll
        for (int nt = 0; nt < 4; ++nt) {
            int r = nh * 64 + nt * 16 + l15;
            const short* bp = &As[cur][r * 32 + ((quad + (r >> 1)) & 3) * 8];
            bf[nt][0] = *(const bf8_t*)bp;
            bf[nt][1] = *(const bf8_t*)(bp + 4096);
            bf[nt][2] = *(const bf8_t*)(bp + 8192);
        }
        #pragma unroll
        for (int mt = 0; mt < 8; ++mt) {
            int mtile = mh * 8 + mt;
            size_t ub = ((((size_t)c * 16 + mtile) * 16 + ks) * 512)
                        + (size_t)lane * 8;
            bf8_t af0 = *(const bf8_t*)(u3 + ub);
            bf8_t af1 = *(const bf8_t*)(u3 + U3_PLANE + ub);
            bf8_t af2 = *(const bf8_t*)(u3 + 2 * U3_PLANE + ub);
            #pragma unroll
            for (int nt = 0; nt < 4; ++nt) {
                f32x4 a = acc[mt][nt];
                a = MFMA16(af0, bf[nt][0], a);   // hh
                a = MFMA16(af0, bf[nt][1], a);   // hm
                a = MFMA16(af1, bf[nt][0], a);   // mh
                a = MFMA16(af1, bf[nt][1], a);   // mm
                a = MFMA16(af0, bf[nt][2], a);   // hl
                a = MFMA16(af2, bf[nt][0], a);   // lh
                acc[mt][nt] = a;
            }
        }
    }

    // Epilogue: scale + bias + mask + exp, write S, fused deterministic
    // per-(wave,m) row-sums over this wave's 64 n.  C/D: col=l15, row=quad*4+r.
    float* Sc = S + (size_t)z * SSZ;
    #pragma unroll
    for (int mt = 0; mt < 8; ++mt) {
        float rs[4] = {0.f, 0.f, 0.f, 0.f};
        #pragma unroll
        for (int nt = 0; nt < 4; ++nt) {
            int nl = nh * 64 + nt * 16 + l15;
            int n = n0 + nl;
            int mem = sMask[nl];
            #pragma unroll
            for (int r = 0; r < 4; ++r) {
                int m = mh * 128 + mt * 16 + quad * 4 + r;
                float sc = SCALE * (acc[mt][nt][r] + sQb[m]);
                float ev = mem ? __expf(sc) : 0.f;
                rs[r] += ev;
                if (n < N_) Sc[(size_t)m * N_ + n] = ev;
            }
        }
        #pragma unroll
        for (int r = 0; r < 4; ++r) {
            float v = rs[r];
            v += __shfl_xor(v, 1); v += __shfl_xor(v, 2);
            v += __shfl_xor(v, 4); v += __shfl_xor(v, 8);
            if (l15 == 0) {
                int m = mh * 128 + mt * 16 + quad * 4 + r;
                Zpart[((size_t)(nc * 2 + nh) * C_ + c) * 256 + m] = v;
            }
        }
    }
}

// ---------------------------------------------------------------------------
// Z(c,m) = sum over 2*NC3 partials. grid = CB blocks x 256 thr.
// ---------------------------------------------------------------------------
__global__ void k_zsum(const float* __restrict__ Zpart, float* __restrict__ Z, int c0) {
    int c = c0 + blockIdx.x;
    int i = c * 256 + threadIdx.x;
    float s = 0.f;
    for (int p = 0; p < 2 * NC3; ++p) s += Zpart[(size_t)p * (C_ * 256) + i];
    Z[i] = s;
}

// ---------------------------------------------------------------------------
// K3: fused head-average + chunk-local top-ns. grid (NCH, B, CB).
// ---------------------------------------------------------------------------
__global__ __launch_bounds__(256) void k_topk1(
        const float* __restrict__ S, const float* __restrict__ Z,
        float2* __restrict__ cand, int c0, int ns) {
    int chunk = blockIdx.x, b = blockIdx.y, z = blockIdx.z;
    const float* Sc = S + (size_t)z * SSZ;
    int tid = threadIdx.x;
    __shared__ float zr[H_];
    if (tid < H_) zr[tid] = 1.0f / Z[(c0 + z) * (B_ * H_) + b * H_ + tid];
    __syncthreads();
    int n0 = chunk * CHUNK;
    float v[2]; int ix[2];
    #pragma unroll
    for (int s = 0; s < 2; ++s) {
        int n = n0 + tid + s * 256;
        float a = -1.f;
        if (n < N_) {
            a = 0.f;
            #pragma unroll
            for (int h = 0; h < H_; ++h)
                a += Sc[(size_t)(b * H_ + h) * N_ + n] * zr[h];
            a *= (1.0f / H_);
        }
        v[s] = a; ix[s] = (n < N_) ? n : N_;
    }
    __shared__ float sv[256];
    __shared__ int   si[256];
    __shared__ int   win;
    for (int j = 0; j < ns; ++j) {
        float bv; int bi;
        if (v[0] > v[1] || (v[0] == v[1] && ix[0] < ix[1])) { bv = v[0]; bi = ix[0]; }
        else                                                 { bv = v[1]; bi = ix[1]; }
        sv[tid] = bv; si[tid] = bi;
        __syncthreads();
        for (int w = 128; w >= 1; w >>= 1) {
            if (tid < w) {
                float v2 = sv[tid + w]; int i2 = si[tid + w];
                if (v2 > sv[tid] || (v2 == sv[tid] && i2 < si[tid])) {
                    sv[tid] = v2; si[tid] = i2;
                }
            }
            __syncthreads();
        }
        if (tid == 0) {
            cand[(((size_t)z * B_ + b) * NCH + chunk) * ns + j] =
                make_float2(sv[0], (float)si[0]);
            win = si[0];
        }
        __syncthreads();
        if (ix[0] == win) v[0] = -2.f;
        if (ix[1] == win) v[1] = -2.f;
        __syncthreads();
    }
}

// ---------------------------------------------------------------------------
// K4: merge NCH*ns candidates -> final top-ns per (b, class). grid (B, CB).
// ---------------------------------------------------------------------------
__global__ __launch_bounds__(256) void k_topk2(
        const float2* __restrict__ cand, float* __restrict__ out, int c0, int ns) {
    int b = blockIdx.x, z = blockIdx.y;
    int c = c0 + z;
    int tid = threadIdx.x;
    int ncand = NCH * ns;
    const float2* cb = cand + ((size_t)z * B_ + b) * ncand;
    float v = -3.f; int ix = N_ + 1;
    if (tid < ncand) { float2 e = cb[tid]; v = e.x; ix = (int)e.y; }
    __shared__ float sv[256];
    __shared__ int   si[256];
    __shared__ int   win;
    for (int j = 0; j < ns; ++j) {
        sv[tid] = v; si[tid] = ix;
        __syncthreads();
        for (int w = 128; w >= 1; w >>= 1) {
            if (tid < w) {
                float v2 = sv[tid + w]; int i2 = si[tid + w];
                if (v2 > sv[tid] || (v2 == sv[tid] && i2 < si[tid])) {
                    sv[tid] = v2; si[tid] = i2;
                }
            }
            __syncthreads();
        }
        if (tid == 0) {
            out[((size_t)b * C_ + c) * ns + j] = (float)si[0];
            out[(size_t)B_ * C_ * ns + ((size_t)b * C_ + c) * ns + j] = sv[0];
            win = si[0];
        }
        __syncthreads();
        if (ix == win) v = -3.f;
        __syncthreads();
    }
}

// ---------------------------------------------------------------------------
extern "C" void kernel_launch(void* const* d_in, const int* in_sizes, int n_in,
                              void* d_out, int out_size, void* d_ws, size_t ws_size,
                              hipStream_t stream) {
    const float* x    = (const float*)d_in[0];  // (B,E)
    const float* A    = (const float*)d_in[1];  // (N,E)
    const int*   mask = (const int*)  d_in[2];  // (N,C)
    const float* Wq   = (const float*)d_in[3];  // (C,E,E)
    const float* bq   = (const float*)d_in[4];  // (C,E)
    const float* Wk   = (const float*)d_in[5];  // (C,E,E)
    const float* bk   = (const float*)d_in[6];  // (C,E)
    float* out = (float*)d_out;

    int ns = out_size / (2 * B_ * C_);          // = n_samples (5)

    // Workspace carve (floats)
    float* ws = (float*)d_ws;
    float* q     = ws;                                    // 131072
    float* u     = q     + (size_t)C_ * B_ * E_;          // 1048576
    float* qb    = u     + (size_t)C_ * B_ * H_ * E_;     // 2048
    float* Z     = qb    + (size_t)C_ * B_ * H_;          // 2048
    float* Zpart = Z     + (size_t)C_ * B_ * H_;          // 2*NC3*8*256 = 643072
    short* u3    = (short*)(Zpart + (size_t)2 * NC3 * C_ * 256);  // 3*1048576 shorts
    short* A3t   = u3 + 3 * U3_PLANE;                             // NC3*16*12288 shorts
    float* S     = (float*)(A3t + (size_t)NC3 * 16 * 12288);
    size_t fixedFloats = (size_t)(S - ws);

    size_t candFloats = (size_t)C_ * B_ * NCH * ns * 2;
    int CB = 8;
    while (CB > 1 &&
           (fixedFloats + (size_t)CB * SSZ + candFloats + 16) * 4 > ws_size)
        CB >>= 1;
    float2* cand = (float2*)(S + (size_t)CB * SSZ);

    k_q2<<<dim3(64, C_), 256, 0, stream>>>(x, Wq, bq, q);
    k_u2<<<dim3(8, H_, C_), 256, 0, stream>>>(q, Wk, bk, u, qb);
    k_split_u3<<<C_ * 16 * 16, 64, 0, stream>>>(u, u3);
    k_split_A3<<<dim3(NC3, 16), 256, 0, stream>>>(A, A3t);

    for (int c0 = 0; c0 < C_; c0 += CB) {
        k_scores_mfma<<<NC3 * CB, 256, 0, stream>>>(u3, A3t, qb, mask, S, Zpart, c0, CB);
        k_zsum<<<CB, 256, 0, stream>>>(Zpart, Z, c0);
        k_topk1<<<dim3(NCH, B_, CB), 256, 0, stream>>>(S, Z, cand, c0, ns);
        k_topk2<<<dim3(B_, CB), 256, 0, stream>>>(cand, out, c0, ns);
    }
}

// Round 8
// 395.881 us; speedup vs baseline: 1.4456x; 1.4456x over previous
//
#include <hip/hip_runtime.h>
#include <math.h>

// Problem constants (fixed by setup_inputs)
#define B_  32
#define N_  20000
#define C_  8
#define E_  512
#define H_  8
#define SCALE 0.125f    // 1/sqrt(64)
#define UNSC  9.765625e-4f   // 1/1024 = 1/(32*32) operand pre-scale undo

#define CHUNK 1024
#define NCH   20       // ceil(20000/1024) (top-k chunking)
#define NC3   157      // ceil(20000/128)  (GEMM n-chunks, BN=128)
#define SSZ ((size_t)B_ * H_ * N_)   // per-class S floats (256*20000)

typedef __attribute__((ext_vector_type(8))) _Float16 h8_t;  // 8 fp16 (4 VGPRs)
typedef __attribute__((ext_vector_type(4))) float f32x4;    // 16x16 MFMA acc

#define MFMAH(a, b, c) __builtin_amdgcn_mfma_f32_16x16x32_f16(a, b, c, 0, 0, 0)

// RNE round-to-fp16, returns bit pattern + rounded value
__device__ inline unsigned short f16_round(float x, float& fv) {
    _Float16 h = (_Float16)x;
    fv = (float)h;
    union { _Float16 hh; unsigned short us; } u;
    u.hh = h;
    return u.us;
}

// ---------------------------------------------------------------------------
// K1a: q(c,b,f) = sum_e x(b,e) * Wq[c][f,e] + bq[c][f]
// Weight-stationary: block = (f-tile of 8, c); thread = (b, f_sub).
// ---------------------------------------------------------------------------
__global__ __launch_bounds__(256) void k_q2(
        const float* __restrict__ x, const float* __restrict__ Wq,
        const float* __restrict__ bq, float* __restrict__ q) {
    int ft = blockIdx.x, c = blockIdx.y;
    int f0 = ft * 8;
    __shared__ float wsm[8][66];
    __shared__ float xs[32][66];
    int tid = threadIdx.x;
    int b = tid & 31, fs = tid >> 5;
    float acc = 0.f;
    const float* W = Wq + (size_t)c * E_ * E_;
    for (int k0 = 0; k0 < E_; k0 += 64) {
        __syncthreads();
        for (int i = tid; i < 512; i += 256)
            wsm[i >> 6][i & 63] = W[(size_t)(f0 + (i >> 6)) * E_ + k0 + (i & 63)];
        for (int i = tid; i < 2048; i += 256)
            xs[i >> 6][i & 63] = x[(size_t)(i >> 6) * E_ + k0 + (i & 63)];
        __syncthreads();
        #pragma unroll
        for (int kk = 0; kk < 64; ++kk)
            acc += xs[b][kk] * wsm[fs][kk];
    }
    q[((size_t)c * B_ + b) * E_ + f0 + fs] = acc + bq[c * E_ + f0 + fs];
}

// ---------------------------------------------------------------------------
// K1b: u(c, m=(b*8+h), e) = sum_d q(c,b,h*64+d) * Wk[c][h*64+d, e]
// block = (e-tile of 64, h, c); thread = (b, e-group of 8). Wk read once.
// ---------------------------------------------------------------------------
__global__ __launch_bounds__(256) void k_u2(
        const float* __restrict__ q, const float* __restrict__ Wk,
        const float* __restrict__ bk, float* __restrict__ u,
        float* __restrict__ qb) {
    int et = blockIdx.x, h = blockIdx.y, c = blockIdx.z;
    int e0 = et * 64;
    __shared__ float qs[32][66];
    __shared__ float wk[64][66];
    int tid = threadIdx.x;
    int b = tid & 31, es = tid >> 5;
    for (int i = tid; i < 2048; i += 256)
        qs[i >> 6][i & 63] = q[((size_t)c * B_ + (i >> 6)) * E_ + h * 64 + (i & 63)];
    const float* W = Wk + (size_t)c * E_ * E_ + (size_t)(h * 64) * E_;
    for (int i = tid; i < 4096; i += 256)
        wk[i >> 6][i & 63] = W[(size_t)(i >> 6) * E_ + e0 + (i & 63)];
    __syncthreads();
    float acc[8] = {};
    for (int d = 0; d < 64; ++d) {
        float qv = qs[b][d];
        #pragma unroll
        for (int j = 0; j < 8; ++j)
            acc[j] += qv * wk[d][es * 8 + j];
    }
    float* urow = u + ((size_t)c * 256 + b * 8 + h) * E_ + e0 + es * 8;
    #pragma unroll
    for (int j = 0; j < 8; ++j) urow[j] = acc[j];
    if (et == 0 && es == 0) {
        float s = 0.f;
        const float* bkr = bk + c * E_ + h * 64;
        for (int d = 0; d < 64; ++d) s += qs[b][d] * bkr[d];
        qb[c * 256 + b * 8 + h] = s;
    }
}

// ---------------------------------------------------------------------------
// Split u*32 into 2 fp16 planes in 16x16x32 A-fragment order:
//   u2[plane][c][mtile 16][kstep 16][lane 64][8]; lane*8+j holds
//   plane( 32*u[c][mtile*16 + (lane&15)][ks*32 + (lane>>4)*8 + j] )
// ---------------------------------------------------------------------------
#define U2P ((size_t)C_ * 16 * 16 * 512)   // 1,048,576 shorts per plane

__global__ void k_split_u2(const float* __restrict__ u, short* __restrict__ u2) {
    int bx = blockIdx.x;
    int ks = bx & 15, mt = (bx >> 4) & 15, c = bx >> 8;
    int lane = threadIdx.x;
    int m  = mt * 16 + (lane & 15);
    int k0 = ks * 32 + (lane >> 4) * 8;
    const float* up = u + ((size_t)c * 256 + m) * 512 + k0;
    size_t base = ((((size_t)c * 16 + mt) * 16 + ks) * 512) + (size_t)lane * 8;
    #pragma unroll
    for (int j = 0; j < 8; ++j) {
        float x = up[j] * 32.0f, fh, fm;
        unsigned short h = f16_round(x, fh);
        unsigned short mm = f16_round(x - fh, fm);
        u2[base + j]       = (short)h;
        u2[U2P + base + j] = (short)mm;
    }
}

// ---------------------------------------------------------------------------
// Split A*32 into 2 fp16 planes, tiled per (nchunk 128, kstep 32):
//   [2][128 n][32 k] per tile (8192 shorts / 16 KB) with the R5 within-row
//   16B-chunk swizzle (chunk q of row n at position (q + (n>>1))&3) ->
//   measured-zero LDS conflicts for the 16x16 B-frag read pattern.
// ---------------------------------------------------------------------------
__global__ void k_split_A2(const float* __restrict__ A, short* __restrict__ A2t) {
    int nc = blockIdx.x, ks = blockIdx.y;
    int tid = threadIdx.x;
    int n = tid >> 1, kg = (tid & 1) * 2;   // logical chunks kg, kg+1 of 4
    int gn = nc * 128 + n;
    const float* ap = A + (size_t)gn * 512 + ks * 32 + kg * 8;
    short vh[2][8], vm[2][8];
    #pragma unroll
    for (int g = 0; g < 2; ++g)
        #pragma unroll
        for (int j = 0; j < 8; ++j) {
            float x = (gn < N_) ? ap[g * 8 + j] * 32.0f : 0.f;
            float fh, fm;
            vh[g][j] = (short)f16_round(x, fh);
            vm[g][j] = (short)f16_round(x - fh, fm);
        }
    short* outp = A2t + ((size_t)nc * 16 + ks) * 8192 + n * 32;
    #pragma unroll
    for (int g = 0; g < 2; ++g) {
        int p = ((kg + g) + (n >> 1)) & 3;
        #pragma unroll
        for (int j = 0; j < 8; ++j) {
            outp[p * 8 + j]        = vh[g][j];
            outp[4096 + p * 8 + j] = vm[g][j];
        }
    }
}

// ---------------------------------------------------------------------------
// Main: S(m,n) = member ? exp(SCALE*(dot/1024 + qb)) : 0, 3-product fp16x2
// (hh, hm, mh) via 16x16x32 f16 MFMA. R5 skeleton: block = 256 thr (4 waves),
// tile M=256 x BN=128 per (class, nchunk); wave w owns m-rows [w*64,w*64+64).
// BK=64: stage TWO 16 KB k-tiles per barrier pair (16 barrier pairs total).
// Fused deterministic per-block row-sums -> Zpart.
// ---------------------------------------------------------------------------
__global__ __launch_bounds__(256, 2) void k_scores_mfma(
        const short* __restrict__ u2, const short* __restrict__ A2t,
        const float* __restrict__ qb, const int* __restrict__ mask,
        float* __restrict__ S, float* __restrict__ Zpart, int c0, int CB) {
    __shared__ __align__(16) short As[16384];   // two [2][128][32] tiles (32 KB)
    __shared__ float sQb[256];
    __shared__ int   sMask[128];
    int bx = blockIdx.x;
    int z  = bx % CB;
    int c  = c0 + z;
    int nc = bx / CB;
    int tid = threadIdx.x;
    int lane = tid & 63, w = tid >> 6;
    int quad = lane >> 4, l15 = lane & 15;
    int n0 = nc * 128;

    sQb[tid] = qb[c * 256 + tid];
    if (tid < 128) {
        int n = n0 + tid;
        sMask[tid] = (n < N_) ? mask[(size_t)n * C_ + c] : 0;
    }

    f32x4 acc[4][8];   // [mt][nt]
    #pragma unroll
    for (int i = 0; i < 4; ++i)
        #pragma unroll
        for (int j = 0; j < 8; ++j)
            acc[i][j] = (f32x4){0.f, 0.f, 0.f, 0.f};

    const float4* tb = (const float4*)((const char*)A2t + (size_t)nc * 262144);

    for (int ks2 = 0; ks2 < 8; ++ks2) {
        __syncthreads();
        // stage two consecutive 16 KB tiles: straight 32 KB linear copy
        const float4* src = tb + ks2 * 2048;
        float4* dst = (float4*)As;
        #pragma unroll
        for (int t = 0; t < 8; ++t) dst[tid + t * 256] = src[tid + t * 256];
        __syncthreads();

        #pragma unroll
        for (int kh = 0; kh < 2; ++kh) {
            int ks = ks2 * 2 + kh;
            const short* Ab = As + kh * 8192;
            // A-fragments (u2) hoisted: 8 global 16B loads, L2-resident
            h8_t af[4][2];
            #pragma unroll
            for (int mt = 0; mt < 4; ++mt) {
                size_t ub = ((((size_t)c * 16 + (w * 4 + mt)) * 16 + ks) * 512)
                            + (size_t)lane * 8;
                af[mt][0] = *(const h8_t*)(u2 + ub);
                af[mt][1] = *(const h8_t*)(u2 + U2P + ub);
            }
            #pragma unroll
            for (int nt = 0; nt < 8; ++nt) {
                int r = nt * 16 + l15;
                const short* bp = Ab + r * 32 + ((quad + (r >> 1)) & 3) * 8;
                h8_t b0 = *(const h8_t*)bp;
                h8_t b1 = *(const h8_t*)(bp + 4096);
                #pragma unroll
                for (int mt = 0; mt < 4; ++mt) {
                    f32x4 a = acc[mt][nt];
                    a = MFMAH(af[mt][0], b0, a);   // hh
                    a = MFMAH(af[mt][0], b1, a);   // hm
                    a = MFMAH(af[mt][1], b0, a);   // mh
                    acc[mt][nt] = a;
                }
            }
        }
    }

    // Epilogue: unscale + bias + mask + exp, write S, fused deterministic
    // row-sums.  C/D: col = lane&15, row = quad*4 + r (m89/m91).
    float* Sc = S + (size_t)z * SSZ;
    #pragma unroll
    for (int mt = 0; mt < 4; ++mt) {
        float rs[4] = {0.f, 0.f, 0.f, 0.f};
        #pragma unroll
        for (int nt = 0; nt < 8; ++nt) {
            int nl = nt * 16 + l15;
            int n = n0 + nl;
            int mem = sMask[nl];
            #pragma unroll
            for (int r = 0; r < 4; ++r) {
                int m = w * 64 + mt * 16 + quad * 4 + r;
                float sc = SCALE * (acc[mt][nt][r] * UNSC + sQb[m]);
                float ev = mem ? __expf(sc) : 0.f;
                rs[r] += ev;
                if (n < N_) Sc[(size_t)m * N_ + n] = ev;
            }
        }
        #pragma unroll
        for (int r = 0; r < 4; ++r) {
            float v = rs[r];
            v += __shfl_xor(v, 1); v += __shfl_xor(v, 2);
            v += __shfl_xor(v, 4); v += __shfl_xor(v, 8);
            if (l15 == 0) {
                int m = w * 64 + mt * 16 + quad * 4 + r;
                Zpart[((size_t)nc * C_ + c) * 256 + m] = v;
            }
        }
    }
}

// ---------------------------------------------------------------------------
// Z(c,m) = sum_nc Zpart(nc,c,m). grid = CB blocks x 256 thr.
// ---------------------------------------------------------------------------
__global__ void k_zsum(const float* __restrict__ Zpart, float* __restrict__ Z, int c0) {
    int c = c0 + blockIdx.x;
    int i = c * 256 + threadIdx.x;
    float s = 0.f;
    for (int nc = 0; nc < NC3; ++nc) s += Zpart[(size_t)nc * (C_ * 256) + i];
    Z[i] = s;
}

// ---------------------------------------------------------------------------
// K3: fused head-average + chunk-local top-ns. grid (NCH, B, CB).
// float4 loads, wave shfl-butterfly reduce (jax tie-break: low index wins).
// ---------------------------------------------------------------------------
__global__ __launch_bounds__(256) void k_topk1(
        const float* __restrict__ S, const float* __restrict__ Z,
        float2* __restrict__ cand, int c0, int ns) {
    int chunk = blockIdx.x, b = blockIdx.y, z = blockIdx.z;
    const float* Sc = S + (size_t)z * SSZ;
    int tid = threadIdx.x;
    __shared__ float zr[H_];
    if (tid < H_) zr[tid] = 1.0f / Z[(c0 + z) * (B_ * H_) + b * H_ + tid];
    __syncthreads();
    int n0 = chunk * CHUNK + tid * 4;
    bool valid = n0 < N_;          // N_ % 4 == 0: float4 fully valid or not
    float4 a = make_float4(0.f, 0.f, 0.f, 0.f);
    if (valid) {
        #pragma unroll
        for (int h = 0; h < H_; ++h) {
            const float4 sv = *(const float4*)&Sc[(size_t)(b * H_ + h) * N_ + n0];
            float wz = zr[h];
            a.x += sv.x * wz; a.y += sv.y * wz; a.z += sv.z * wz; a.w += sv.w * wz;
        }
    }
    float v[4]; int ix[4];
    v[0] = valid ? a.x * 0.125f : -1.f;
    v[1] = valid ? a.y * 0.125f : -1.f;
    v[2] = valid ? a.z * 0.125f : -1.f;
    v[3] = valid ? a.w * 0.125f : -1.f;
    #pragma unroll
    for (int t = 0; t < 4; ++t) ix[t] = valid ? n0 + t : N_;

    __shared__ float wv[4];
    __shared__ int   wi[4];
    __shared__ int   winS;
    int lane = tid & 63, w = tid >> 6;
    for (int j = 0; j < ns; ++j) {
        float bv = v[0]; int bi = ix[0];
        #pragma unroll
        for (int t = 1; t < 4; ++t)
            if (v[t] > bv || (v[t] == bv && ix[t] < bi)) { bv = v[t]; bi = ix[t]; }
        #pragma unroll
        for (int off = 1; off < 64; off <<= 1) {
            float ov = __shfl_xor(bv, off, 64);
            int   oi = __shfl_xor(bi, off, 64);
            if (ov > bv || (ov == bv && oi < bi)) { bv = ov; bi = oi; }
        }
        if (lane == 0) { wv[w] = bv; wi[w] = bi; }
        __syncthreads();
        if (tid == 0) {
            float fv = wv[0]; int fi = wi[0];
            #pragma unroll
            for (int t = 1; t < 4; ++t)
                if (wv[t] > fv || (wv[t] == fv && wi[t] < fi)) { fv = wv[t]; fi = wi[t]; }
            cand[(((size_t)z * B_ + b) * NCH + chunk) * ns + j] =
                make_float2(fv, (float)fi);
            winS = fi;
        }
        __syncthreads();
        int wn = winS;
        #pragma unroll
        for (int t = 0; t < 4; ++t)
            if (ix[t] == wn) v[t] = -2.f;
    }
}

// ---------------------------------------------------------------------------
// K4: merge NCH*ns candidates -> final top-ns per (b, class). grid (B, CB).
// ---------------------------------------------------------------------------
__global__ __launch_bounds__(256) void k_topk2(
        const float2* __restrict__ cand, float* __restrict__ out, int c0, int ns) {
    int b = blockIdx.x, z = blockIdx.y;
    int c = c0 + z;
    int tid = threadIdx.x;
    int ncand = NCH * ns;   // 100
    const float2* cb = cand + ((size_t)z * B_ + b) * ncand;
    float v = -3.f; int ix = N_ + 1;
    if (tid < ncand) { float2 e = cb[tid]; v = e.x; ix = (int)e.y; }
    __shared__ float sv[256];
    __shared__ int   si[256];
    __shared__ int   win;
    for (int j = 0; j < ns; ++j) {
        sv[tid] = v; si[tid] = ix;
        __syncthreads();
        for (int w = 128; w >= 1; w >>= 1) {
            if (tid < w) {
                float v2 = sv[tid + w]; int i2 = si[tid + w];
                if (v2 > sv[tid] || (v2 == sv[tid] && i2 < si[tid])) {
                    sv[tid] = v2; si[tid] = i2;
                }
            }
            __syncthreads();
        }
        if (tid == 0) {
            out[((size_t)b * C_ + c) * ns + j] = (float)si[0];
            out[(size_t)B_ * C_ * ns + ((size_t)b * C_ + c) * ns + j] = sv[0];
            win = si[0];
        }
        __syncthreads();
        if (ix == win) v = -3.f;
        __syncthreads();
    }
}

// ---------------------------------------------------------------------------
extern "C" void kernel_launch(void* const* d_in, const int* in_sizes, int n_in,
                              void* d_out, int out_size, void* d_ws, size_t ws_size,
                              hipStream_t stream) {
    const float* x    = (const float*)d_in[0];  // (B,E)
    const float* A    = (const float*)d_in[1];  // (N,E)
    const int*   mask = (const int*)  d_in[2];  // (N,C)
    const float* Wq   = (const float*)d_in[3];  // (C,E,E)
    const float* bq   = (const float*)d_in[4];  // (C,E)
    const float* Wk   = (const float*)d_in[5];  // (C,E,E)
    const float* bk   = (const float*)d_in[6];  // (C,E)
    float* out = (float*)d_out;

    int ns = out_size / (2 * B_ * C_);          // = n_samples (5)

    // Workspace carve (floats)
    float* ws = (float*)d_ws;
    float* q     = ws;                                    // 131072
    float* u     = q     + (size_t)C_ * B_ * E_;          // 1048576
    float* qb    = u     + (size_t)C_ * B_ * H_ * E_;     // 2048
    float* Z     = qb    + (size_t)C_ * B_ * H_;          // 2048
    float* Zpart = Z     + (size_t)C_ * B_ * H_;          // NC3*8*256 = 321536
    short* u2    = (short*)(Zpart + (size_t)NC3 * C_ * 256);   // 2*1048576 shorts
    short* A2t   = u2 + 2 * U2P;                               // NC3*16*8192 shorts
    float* S     = (float*)(A2t + (size_t)NC3 * 16 * 8192);
    size_t fixedFloats = (size_t)(S - ws);

    size_t candFloats = (size_t)C_ * B_ * NCH * ns * 2;
    int CB = 8;
    while (CB > 1 &&
           (fixedFloats + (size_t)CB * SSZ + candFloats + 16) * 4 > ws_size)
        CB >>= 1;
    float2* cand = (float2*)(S + (size_t)CB * SSZ);

    k_q2<<<dim3(64, C_), 256, 0, stream>>>(x, Wq, bq, q);
    k_u2<<<dim3(8, H_, C_), 256, 0, stream>>>(q, Wk, bk, u, qb);
    k_split_u2<<<C_ * 16 * 16, 64, 0, stream>>>(u, u2);
    k_split_A2<<<dim3(NC3, 16), 256, 0, stream>>>(A, A2t);

    for (int c0 = 0; c0 < C_; c0 += CB) {
        k_scores_mfma<<<NC3 * CB, 256, 0, stream>>>(u2, A2t, qb, mask, S, Zpart, c0, CB);
        k_zsum<<<CB, 256, 0, stream>>>(Zpart, Z, c0);
        k_topk1<<<dim3(NCH, B_, CB), 256, 0, stream>>>(S, Z, cand, c0, ns);
        k_topk2<<<dim3(B_, CB), 256, 0, stream>>>(cand, out, c0, ns);
    }
}

// Round 9
// 388.807 us; speedup vs baseline: 1.4719x; 1.0182x over previous
//
#include <hip/hip_runtime.h>
#include <math.h>

// Problem constants (fixed by setup_inputs)
#define B_  32
#define N_  20000
#define C_  8
#define E_  512
#define H_  8
#define SCALE 0.125f    // 1/sqrt(64)
#define UNSC  9.765625e-4f   // 1/1024 = 1/(32*32) operand pre-scale undo

#define CHUNK 1024
#define NCH   20       // ceil(20000/1024) (top-k chunking)
#define NC3   157      // ceil(20000/128)  (GEMM n-chunks, BN=128)
#define NCG   20       // ceil(NC3/8) nc-groups for XCD swizzle
#define SSZ ((size_t)B_ * H_ * N_)   // per-class S floats (256*20000)

typedef __attribute__((ext_vector_type(8))) _Float16 h8_t;  // 8 fp16 (4 VGPRs)
typedef __attribute__((ext_vector_type(8))) short   s8_t;   // 8 shorts (16 B)
typedef __attribute__((ext_vector_type(4))) float f32x4;    // 16x16 MFMA acc

#define MFMAH(a, b, c) __builtin_amdgcn_mfma_f32_16x16x32_f16(a, b, c, 0, 0, 0)

// async global->LDS, 16B per lane, wave-uniform LDS base + lane*16
#define GLOAD_LDS16(g, l)                                              \
    __builtin_amdgcn_global_load_lds(                                  \
        (const __attribute__((address_space(1))) unsigned int*)(g),    \
        (__attribute__((address_space(3))) unsigned int*)(l), 16, 0, 0)

// RNE round-to-fp16, returns bit pattern + rounded value
__device__ inline unsigned short f16_round(float x, float& fv) {
    _Float16 h = (_Float16)x;
    fv = (float)h;
    union { _Float16 hh; unsigned short us; } u;
    u.hh = h;
    return u.us;
}

// ---------------------------------------------------------------------------
// K1a: q(c,b,f) = sum_e x(b,e) * Wq[c][f,e] + bq[c][f]
// Weight-stationary: block = (f-tile of 8, c); thread = (b, f_sub).
// ---------------------------------------------------------------------------
__global__ __launch_bounds__(256) void k_q2(
        const float* __restrict__ x, const float* __restrict__ Wq,
        const float* __restrict__ bq, float* __restrict__ q) {
    int ft = blockIdx.x, c = blockIdx.y;
    int f0 = ft * 8;
    __shared__ float wsm[8][66];
    __shared__ float xs[32][66];
    int tid = threadIdx.x;
    int b = tid & 31, fs = tid >> 5;
    float acc = 0.f;
    const float* W = Wq + (size_t)c * E_ * E_;
    for (int k0 = 0; k0 < E_; k0 += 64) {
        __syncthreads();
        for (int i = tid; i < 512; i += 256)
            wsm[i >> 6][i & 63] = W[(size_t)(f0 + (i >> 6)) * E_ + k0 + (i & 63)];
        for (int i = tid; i < 2048; i += 256)
            xs[i >> 6][i & 63] = x[(size_t)(i >> 6) * E_ + k0 + (i & 63)];
        __syncthreads();
        #pragma unroll
        for (int kk = 0; kk < 64; ++kk)
            acc += xs[b][kk] * wsm[fs][kk];
    }
    q[((size_t)c * B_ + b) * E_ + f0 + fs] = acc + bq[c * E_ + f0 + fs];
}

// ---------------------------------------------------------------------------
// K1b: u(c, m=(b*8+h), e) = sum_d q(c,b,h*64+d) * Wk[c][h*64+d, e]
// block = (e-tile of 64, h, c); thread = (b, e-group of 8). Wk read once.
// ---------------------------------------------------------------------------
__global__ __launch_bounds__(256) void k_u2(
        const float* __restrict__ q, const float* __restrict__ Wk,
        const float* __restrict__ bk, float* __restrict__ u,
        float* __restrict__ qb) {
    int et = blockIdx.x, h = blockIdx.y, c = blockIdx.z;
    int e0 = et * 64;
    __shared__ float qs[32][66];
    __shared__ float wk[64][66];
    int tid = threadIdx.x;
    int b = tid & 31, es = tid >> 5;
    for (int i = tid; i < 2048; i += 256)
        qs[i >> 6][i & 63] = q[((size_t)c * B_ + (i >> 6)) * E_ + h * 64 + (i & 63)];
    const float* W = Wk + (size_t)c * E_ * E_ + (size_t)(h * 64) * E_;
    for (int i = tid; i < 4096; i += 256)
        wk[i >> 6][i & 63] = W[(size_t)(i >> 6) * E_ + e0 + (i & 63)];
    __syncthreads();
    float acc[8] = {};
    for (int d = 0; d < 64; ++d) {
        float qv = qs[b][d];
        #pragma unroll
        for (int j = 0; j < 8; ++j)
            acc[j] += qv * wk[d][es * 8 + j];
    }
    float* urow = u + ((size_t)c * 256 + b * 8 + h) * E_ + e0 + es * 8;
    #pragma unroll
    for (int j = 0; j < 8; ++j) urow[j] = acc[j];
    if (et == 0 && es == 0) {
        float s = 0.f;
        const float* bkr = bk + c * E_ + h * 64;
        for (int d = 0; d < 64; ++d) s += qs[b][d] * bkr[d];
        qb[c * 256 + b * 8 + h] = s;
    }
}

// ---------------------------------------------------------------------------
// Split u*32 into 2 fp16 planes in 16x16x32 A-fragment order:
//   u2[plane][c][mtile 16][kstep 16][lane 64][8]; lane*8+j holds
//   plane( 32*u[c][mtile*16 + (lane&15)][ks*32 + (lane>>4)*8 + j] )
// ---------------------------------------------------------------------------
#define U2P ((size_t)C_ * 16 * 16 * 512)   // 1,048,576 shorts per plane

__global__ void k_split_u2(const float* __restrict__ u, short* __restrict__ u2) {
    int bx = blockIdx.x;
    int ks = bx & 15, mt = (bx >> 4) & 15, c = bx >> 8;
    int lane = threadIdx.x;
    int m  = mt * 16 + (lane & 15);
    int k0 = ks * 32 + (lane >> 4) * 8;
    const float* up = u + ((size_t)c * 256 + m) * 512 + k0;
    size_t base = ((((size_t)c * 16 + mt) * 16 + ks) * 512) + (size_t)lane * 8;
    s8_t vh, vm;
    #pragma unroll
    for (int j = 0; j < 8; ++j) {
        float x = up[j] * 32.0f, fh, fm;
        vh[j] = (short)f16_round(x, fh);
        vm[j] = (short)f16_round(x - fh, fm);
    }
    *(s8_t*)(u2 + base)       = vh;
    *(s8_t*)(u2 + U2P + base) = vm;
}

// ---------------------------------------------------------------------------
// Split A*32 into 2 fp16 planes, tiled per (nchunk 128, kstep 32):
//   [2][128 n][32 k] per tile (8192 shorts / 16 KB) with the R5 within-row
//   16B-chunk swizzle (chunk q of row n at position (q + (n>>1))&3) ->
//   measured-zero LDS conflicts for the 16x16 B-frag read pattern.
// 16 B vector stores (R7 pattern).
// ---------------------------------------------------------------------------
__global__ void k_split_A2(const float* __restrict__ A, short* __restrict__ A2t) {
    int nc = blockIdx.x, ks = blockIdx.y;
    int tid = threadIdx.x;
    int n = tid >> 1, kg = (tid & 1) * 2;   // logical chunks kg, kg+1 of 4
    int gn = nc * 128 + n;
    const float* ap = A + (size_t)gn * 512 + ks * 32 + kg * 8;
    s8_t vh[2], vm[2];
    #pragma unroll
    for (int g = 0; g < 2; ++g)
        #pragma unroll
        for (int j = 0; j < 8; ++j) {
            float x = (gn < N_) ? ap[g * 8 + j] * 32.0f : 0.f;
            float fh, fm;
            vh[g][j] = (short)f16_round(x, fh);
            vm[g][j] = (short)f16_round(x - fh, fm);
        }
    short* outp = A2t + ((size_t)nc * 16 + ks) * 8192 + n * 32;
    #pragma unroll
    for (int g = 0; g < 2; ++g) {
        int p = ((kg + g) + (n >> 1)) & 3;
        *(s8_t*)(outp + p * 8)        = vh[g];
        *(s8_t*)(outp + 4096 + p * 8) = vm[g];
    }
}

// ---------------------------------------------------------------------------
// Main: S(m,n) = member ? exp(SCALE*(dot/1024 + qb)) : 0, 3-product fp16x2
// (hh, hm, mh) via 16x16x32 f16 MFMA. R8 skeleton: block = 256 thr (4 waves),
// tile M=256 x BN=128 per (class, nchunk); wave w owns m-rows [w*64,w*64+64).
// BK=64: two 16 KB k-tiles staged per barrier pair via global_load_lds DMA.
// XCD swizzle: bx -> (x=bx&7, z, g), nc = g*8+x, so the 8 class-blocks of an
// nc share XCD residue x -> A2t tile fetched once per XCD, reused in L2.
// Fused deterministic per-block row-sums -> Zpart.
// ---------------------------------------------------------------------------
__global__ __launch_bounds__(256, 2) void k_scores_mfma(
        const short* __restrict__ u2, const short* __restrict__ A2t,
        const float* __restrict__ qb, const int* __restrict__ mask,
        float* __restrict__ S, float* __restrict__ Zpart, int c0, int CB) {
    __shared__ __align__(16) short As[16384];   // two [2][128][32] tiles (32 KB)
    __shared__ float sQb[256];
    __shared__ int   sMask[128];
    int bx = blockIdx.x;
    int x    = bx & 7;
    int rest = bx >> 3;
    int z    = rest % CB;
    int g    = rest / CB;
    int nc   = g * 8 + x;
    if (nc >= NC3) return;
    int c  = c0 + z;
    int tid = threadIdx.x;
    int lane = tid & 63, w = tid >> 6;
    int quad = lane >> 4, l15 = lane & 15;
    int n0 = nc * 128;

    sQb[tid] = qb[c * 256 + tid];
    if (tid < 128) {
        int n = n0 + tid;
        sMask[tid] = (n < N_) ? mask[(size_t)n * C_ + c] : 0;
    }

    f32x4 acc[4][8];   // [mt][nt]
    #pragma unroll
    for (int i = 0; i < 4; ++i)
        #pragma unroll
        for (int j = 0; j < 8; ++j)
            acc[i][j] = (f32x4){0.f, 0.f, 0.f, 0.f};

    const char* tb = (const char*)A2t + (size_t)nc * 262144;

    for (int ks2 = 0; ks2 < 8; ++ks2) {
        __syncthreads();   // all waves done reading As
        // async DMA the next 32 KB (two 16 KB k-tiles): 32 segs of 1024 B
        const char* src = tb + (size_t)ks2 * 32768;
        #pragma unroll
        for (int t = 0; t < 8; ++t) {
            int seg = w * 8 + t;
            GLOAD_LDS16(src + (size_t)seg * 1024 + lane * 16,
                        (char*)As + seg * 1024);
        }
        __syncthreads();   // compiler drains vmcnt(0) before barrier

        #pragma unroll
        for (int kh = 0; kh < 2; ++kh) {
            int ks = ks2 * 2 + kh;
            const short* Ab = As + kh * 8192;
            // A-fragments (u2) hoisted: 8 global 16B loads, L2/LLC-resident
            h8_t af[4][2];
            #pragma unroll
            for (int mt = 0; mt < 4; ++mt) {
                size_t ub = ((((size_t)c * 16 + (w * 4 + mt)) * 16 + ks) * 512)
                            + (size_t)lane * 8;
                af[mt][0] = *(const h8_t*)(u2 + ub);
                af[mt][1] = *(const h8_t*)(u2 + U2P + ub);
            }
            #pragma unroll
            for (int nt = 0; nt < 8; ++nt) {
                int r = nt * 16 + l15;
                const short* bp = Ab + r * 32 + ((quad + (r >> 1)) & 3) * 8;
                h8_t b0 = *(const h8_t*)bp;
                h8_t b1 = *(const h8_t*)(bp + 4096);
                #pragma unroll
                for (int mt = 0; mt < 4; ++mt) {
                    f32x4 a = acc[mt][nt];
                    a = MFMAH(af[mt][0], b0, a);   // hh
                    a = MFMAH(af[mt][0], b1, a);   // hm
                    a = MFMAH(af[mt][1], b0, a);   // mh
                    acc[mt][nt] = a;
                }
            }
        }
    }

    // Epilogue: unscale + bias + mask + exp, write S, fused deterministic
    // row-sums.  C/D: col = lane&15, row = quad*4 + r (m89/m91).
    float* Sc = S + (size_t)z * SSZ;
    #pragma unroll
    for (int mt = 0; mt < 4; ++mt) {
        float rs[4] = {0.f, 0.f, 0.f, 0.f};
        #pragma unroll
        for (int nt = 0; nt < 8; ++nt) {
            int nl = nt * 16 + l15;
            int n = n0 + nl;
            int mem = sMask[nl];
            #pragma unroll
            for (int r = 0; r < 4; ++r) {
                int m = w * 64 + mt * 16 + quad * 4 + r;
                float sc = SCALE * (acc[mt][nt][r] * UNSC + sQb[m]);
                float ev = mem ? __expf(sc) : 0.f;
                rs[r] += ev;
                if (n < N_) Sc[(size_t)m * N_ + n] = ev;
            }
        }
        #pragma unroll
        for (int r = 0; r < 4; ++r) {
            float v = rs[r];
            v += __shfl_xor(v, 1); v += __shfl_xor(v, 2);
            v += __shfl_xor(v, 4); v += __shfl_xor(v, 8);
            if (l15 == 0) {
                int m = w * 64 + mt * 16 + quad * 4 + r;
                Zpart[((size_t)nc * C_ + c) * 256 + m] = v;
            }
        }
    }
}

// ---------------------------------------------------------------------------
// Z(c,m) = sum_nc Zpart(nc,c,m). grid = CB blocks x 256 thr.
// ---------------------------------------------------------------------------
__global__ void k_zsum(const float* __restrict__ Zpart, float* __restrict__ Z, int c0) {
    int c = c0 + blockIdx.x;
    int i = c * 256 + threadIdx.x;
    float s = 0.f;
    for (int nc = 0; nc < NC3; ++nc) s += Zpart[(size_t)nc * (C_ * 256) + i];
    Z[i] = s;
}

// ---------------------------------------------------------------------------
// K3: fused head-average + chunk-local top-ns. grid (NCH, B, CB).
// float4 loads, wave shfl-butterfly reduce (jax tie-break: low index wins).
// ---------------------------------------------------------------------------
__global__ __launch_bounds__(256) void k_topk1(
        const float* __restrict__ S, const float* __restrict__ Z,
        float2* __restrict__ cand, int c0, int ns) {
    int chunk = blockIdx.x, b = blockIdx.y, z = blockIdx.z;
    const float* Sc = S + (size_t)z * SSZ;
    int tid = threadIdx.x;
    __shared__ float zr[H_];
    if (tid < H_) zr[tid] = 1.0f / Z[(c0 + z) * (B_ * H_) + b * H_ + tid];
    __syncthreads();
    int n0 = chunk * CHUNK + tid * 4;
    bool valid = n0 < N_;          // N_ % 4 == 0: float4 fully valid or not
    float4 a = make_float4(0.f, 0.f, 0.f, 0.f);
    if (valid) {
        #pragma unroll
        for (int h = 0; h < H_; ++h) {
            const float4 sv = *(const float4*)&Sc[(size_t)(b * H_ + h) * N_ + n0];
            float wz = zr[h];
            a.x += sv.x * wz; a.y += sv.y * wz; a.z += sv.z * wz; a.w += sv.w * wz;
        }
    }
    float v[4]; int ix[4];
    v[0] = valid ? a.x * 0.125f : -1.f;
    v[1] = valid ? a.y * 0.125f : -1.f;
    v[2] = valid ? a.z * 0.125f : -1.f;
    v[3] = valid ? a.w * 0.125f : -1.f;
    #pragma unroll
    for (int t = 0; t < 4; ++t) ix[t] = valid ? n0 + t : N_;

    __shared__ float wv[4];
    __shared__ int   wi[4];
    __shared__ int   winS;
    int lane = tid & 63, w = tid >> 6;
    for (int j = 0; j < ns; ++j) {
        float bv = v[0]; int bi = ix[0];
        #pragma unroll
        for (int t = 1; t < 4; ++t)
            if (v[t] > bv || (v[t] == bv && ix[t] < bi)) { bv = v[t]; bi = ix[t]; }
        #pragma unroll
        for (int off = 1; off < 64; off <<= 1) {
            float ov = __shfl_xor(bv, off, 64);
            int   oi = __shfl_xor(bi, off, 64);
            if (ov > bv || (ov == bv && oi < bi)) { bv = ov; bi = oi; }
        }
        if (lane == 0) { wv[w] = bv; wi[w] = bi; }
        __syncthreads();
        if (tid == 0) {
            float fv = wv[0]; int fi = wi[0];
            #pragma unroll
            for (int t = 1; t < 4; ++t)
                if (wv[t] > fv || (wv[t] == fv && wi[t] < fi)) { fv = wv[t]; fi = wi[t]; }
            cand[(((size_t)z * B_ + b) * NCH + chunk) * ns + j] =
                make_float2(fv, (float)fi);
            winS = fi;
        }
        __syncthreads();
        int wn = winS;
        #pragma unroll
        for (int t = 0; t < 4; ++t)
            if (ix[t] == wn) v[t] = -2.f;
    }
}

// ---------------------------------------------------------------------------
// K4: merge NCH*ns candidates -> final top-ns per (b, class). grid (B, CB).
// ---------------------------------------------------------------------------
__global__ __launch_bounds__(256) void k_topk2(
        const float2* __restrict__ cand, float* __restrict__ out, int c0, int ns) {
    int b = blockIdx.x, z = blockIdx.y;
    int c = c0 + z;
    int tid = threadIdx.x;
    int ncand = NCH * ns;   // 100
    const float2* cb = cand + ((size_t)z * B_ + b) * ncand;
    float v = -3.f; int ix = N_ + 1;
    if (tid < ncand) { float2 e = cb[tid]; v = e.x; ix = (int)e.y; }
    __shared__ float sv[256];
    __shared__ int   si[256];
    __shared__ int   win;
    for (int j = 0; j < ns; ++j) {
        sv[tid] = v; si[tid] = ix;
        __syncthreads();
        for (int w = 128; w >= 1; w >>= 1) {
            if (tid < w) {
                float v2 = sv[tid + w]; int i2 = si[tid + w];
                if (v2 > sv[tid] || (v2 == sv[tid] && i2 < si[tid])) {
                    sv[tid] = v2; si[tid] = i2;
                }
            }
            __syncthreads();
        }
        if (tid == 0) {
            out[((size_t)b * C_ + c) * ns + j] = (float)si[0];
            out[(size_t)B_ * C_ * ns + ((size_t)b * C_ + c) * ns + j] = sv[0];
            win = si[0];
        }
        __syncthreads();
        if (ix == win) v = -3.f;
        __syncthreads();
    }
}

// ---------------------------------------------------------------------------
extern "C" void kernel_launch(void* const* d_in, const int* in_sizes, int n_in,
                              void* d_out, int out_size, void* d_ws, size_t ws_size,
                              hipStream_t stream) {
    const float* x    = (const float*)d_in[0];  // (B,E)
    const float* A    = (const float*)d_in[1];  // (N,E)
    const int*   mask = (const int*)  d_in[2];  // (N,C)
    const float* Wq   = (const float*)d_in[3];  // (C,E,E)
    const float* bq   = (const float*)d_in[4];  // (C,E)
    const float* Wk   = (const float*)d_in[5];  // (C,E,E)
    const float* bk   = (const float*)d_in[6];  // (C,E)
    float* out = (float*)d_out;

    int ns = out_size / (2 * B_ * C_);          // = n_samples (5)

    // Workspace carve (floats)
    float* ws = (float*)d_ws;
    float* q     = ws;                                    // 131072
    float* u     = q     + (size_t)C_ * B_ * E_;          // 1048576
    float* qb    = u     + (size_t)C_ * B_ * H_ * E_;     // 2048
    float* Z     = qb    + (size_t)C_ * B_ * H_;          // 2048
    float* Zpart = Z     + (size_t)C_ * B_ * H_;          // NC3*8*256 = 321536
    short* u2    = (short*)(Zpart + (size_t)NC3 * C_ * 256);   // 2*1048576 shorts
    short* A2t   = u2 + 2 * U2P;                               // NC3*16*8192 shorts
    float* S     = (float*)(A2t + (size_t)NC3 * 16 * 8192);
    size_t fixedFloats = (size_t)(S - ws);

    size_t candFloats = (size_t)C_ * B_ * NCH * ns * 2;
    int CB = 8;
    while (CB > 1 &&
           (fixedFloats + (size_t)CB * SSZ + candFloats + 16) * 4 > ws_size)
        CB >>= 1;
    float2* cand = (float2*)(S + (size_t)CB * SSZ);

    k_q2<<<dim3(64, C_), 256, 0, stream>>>(x, Wq, bq, q);
    k_u2<<<dim3(8, H_, C_), 256, 0, stream>>>(q, Wk, bk, u, qb);
    k_split_u2<<<C_ * 16 * 16, 64, 0, stream>>>(u, u2);
    k_split_A2<<<dim3(NC3, 16), 256, 0, stream>>>(A, A2t);

    for (int c0 = 0; c0 < C_; c0 += CB) {
        k_scores_mfma<<<NCG * 8 * CB, 256, 0, stream>>>(u2, A2t, qb, mask, S, Zpart, c0, CB);
        k_zsum<<<CB, 256, 0, stream>>>(Zpart, Z, c0);
        k_topk1<<<dim3(NCH, B_, CB), 256, 0, stream>>>(S, Z, cand, c0, ns);
        k_topk2<<<dim3(B_, CB), 256, 0, stream>>>(cand, out, c0, ns);
    }
}